// Round 11
// baseline (830.923 us; speedup 1.0000x reference)
//
#include <hip/hip_runtime.h>
#include <stdint.h>

#define BATCH 4
#define NPTS 8192
#define KNN_K 16
#define GRID 24
#define NCELL (GRID * GRID * GRID)  // 13824
#define NCELLP (NCELL + 8)          // offs stride (sentinel slot)

typedef unsigned long long u64;
typedef unsigned short u16;

// ws layout (bytes)
#define WS_IDX 0u          // u16[4*8192*16]            = 1,048,576
#define WS_LT 1048576u     // float[4*8192*192]         = 25,165,824
#define WS_CNT 26214400u   // int[4*13824]              = 221,184
#define WS_OFF 26435584u   // int[4*13832]              = 221,312
#define WS_CUR 26656896u   // int[4*13824]              = 221,184
#define WS_SP 26878080u    // float4[4*8192]            = 524,288
#define WS_GP 27402368u    // float[4*8]                = 128
#define WS_SIDX 27402496u  // u16[4*8192]               = 65,536

__device__ __forceinline__ int cellof(float v, float o, float invs) {
  int c = (int)((v - o) * invs);
  return c < GRID - 1 ? c : GRID - 1;
}

// ---------------------------------------------------------------- K0: bbox + zero counters
__global__ __launch_bounds__(256) void k_minmax(const float4* __restrict__ xytp,
                                                float* __restrict__ gp,
                                                int* __restrict__ cnt) {
  const int b = blockIdx.x, t = threadIdx.x;
  for (int c = t; c < NCELL; c += 256) cnt[b * NCELL + c] = 0;
  const float4* pb = xytp + (b << 13);
  float mnx = INFINITY, mny = INFINITY, mnz = INFINITY;
  float mxx = -INFINITY, mxy = -INFINITY, mxz = -INFINITY;
  for (int i = t; i < NPTS; i += 256) {
    float4 p = pb[i];
    mnx = fminf(mnx, p.x); mny = fminf(mny, p.y); mnz = fminf(mnz, p.z);
    mxx = fmaxf(mxx, p.x); mxy = fmaxf(mxy, p.y); mxz = fmaxf(mxz, p.z);
  }
#pragma unroll
  for (int d = 1; d < 64; d <<= 1) {
    mnx = fminf(mnx, __shfl_xor(mnx, d)); mny = fminf(mny, __shfl_xor(mny, d));
    mnz = fminf(mnz, __shfl_xor(mnz, d)); mxx = fmaxf(mxx, __shfl_xor(mxx, d));
    mxy = fmaxf(mxy, __shfl_xor(mxy, d)); mxz = fmaxf(mxz, __shfl_xor(mxz, d));
  }
  __shared__ float red[4][6];
  const int lane = t & 63, wv = t >> 6;
  if (lane == 0) {
    red[wv][0] = mnx; red[wv][1] = mny; red[wv][2] = mnz;
    red[wv][3] = mxx; red[wv][4] = mxy; red[wv][5] = mxz;
  }
  __syncthreads();
  if (t == 0) {
    for (int w = 1; w < 4; ++w) {
      red[0][0] = fminf(red[0][0], red[w][0]);
      red[0][1] = fminf(red[0][1], red[w][1]);
      red[0][2] = fminf(red[0][2], red[w][2]);
      red[0][3] = fmaxf(red[0][3], red[w][3]);
      red[0][4] = fmaxf(red[0][4], red[w][4]);
      red[0][5] = fmaxf(red[0][5], red[w][5]);
    }
    float rmax = fmaxf(red[0][3] - red[0][0],
                       fmaxf(red[0][4] - red[0][1], red[0][5] - red[0][2]));
    float s = rmax / (float)GRID;
    float* g = gp + b * 8;
    g[0] = red[0][0]; g[1] = red[0][1]; g[2] = red[0][2];
    g[3] = s; g[4] = 1.0f / s;
  }
}

// ---------------------------------------------------------------- K2: count
__global__ __launch_bounds__(256) void k_count(const float4* __restrict__ xytp,
                                               const float* __restrict__ gp,
                                               int* __restrict__ cnt) {
  int i = blockIdx.x * 256 + threadIdx.x;
  int b = i >> 13;
  const float* g = gp + b * 8;
  float4 p = xytp[i];
  int cx = cellof(p.x, g[0], g[4]);
  int cy = cellof(p.y, g[1], g[4]);
  int cz = cellof(p.z, g[2], g[4]);
  atomicAdd(&cnt[b * NCELL + (cz * GRID + cy) * GRID + cx], 1);
}

// ---------------------------------------------------------------- K3: exclusive scan
__global__ __launch_bounds__(1024) void k_scan(const int* __restrict__ cnt,
                                               int* __restrict__ offs,
                                               int* __restrict__ curs) {
  __shared__ int wsum[16];
  const int b = blockIdx.x, t = threadIdx.x;
  const int base = b * NCELL;
  const int base2 = b * NCELLP;
  const int lo = t * 14;
  const int hi = lo + 14 < NCELL ? lo + 14 : NCELL;
  int s = 0;
  for (int c = lo; c < hi; ++c) s += cnt[base + c];
  const int lane = t & 63, wv = t >> 6;
  int v = s;
#pragma unroll
  for (int d = 1; d < 64; d <<= 1) {
    int u = __shfl_up(v, d);
    if (lane >= d) v += u;
  }
  if (lane == 63) wsum[wv] = v;
  __syncthreads();
  if (wv == 0 && lane < 16) {
    int x = wsum[lane];
#pragma unroll
    for (int d = 1; d < 16; d <<= 1) {
      int u = __shfl_up(x, d, 16);
      if (lane >= d) x += u;
    }
    wsum[lane] = x;
  }
  __syncthreads();
  int excl = (wv > 0 ? wsum[wv - 1] : 0) + v - s;
  for (int c = lo; c < hi; ++c) {
    offs[base2 + c] = excl;
    curs[base + c] = excl;
    excl += cnt[base + c];
  }
  if (hi == NCELL) offs[base2 + NCELL] = excl;  // == NPTS
}

// ---------------------------------------------------------------- K4: scatter
__global__ __launch_bounds__(256) void k_scatter(const float4* __restrict__ xytp,
                                                 const float* __restrict__ gp,
                                                 int* __restrict__ curs,
                                                 float4* __restrict__ spts,
                                                 u16* __restrict__ sidx) {
  int i = blockIdx.x * 256 + threadIdx.x;
  int b = i >> 13, n = i & 8191;
  const float* g = gp + b * 8;
  float4 p = xytp[i];
  int cx = cellof(p.x, g[0], g[4]);
  int cy = cellof(p.y, g[1], g[4]);
  int cz = cellof(p.z, g[2], g[4]);
  int pos = atomicAdd(&curs[b * NCELL + (cz * GRID + cy) * GRID + cx], 1);
  float sq = fmaf(p.z, p.z, fmaf(p.y, p.y, p.x * p.x));
  spts[(b << 13) + pos] = make_float4(p.x, p.y, p.z, sq);
  sidx[(b << 13) + pos] = (u16)n;
}

// ---------------------------------------------------------------- K5: grid KNN query
// 128-thr blocks (8 teams of 16 lanes).  Two passes:
// Pass 1 (cheap): expand shells keeping only a per-lane 3-deep min cascade
//   (genuine distinct distances).  Stop at the first r where the team holds
//   >=16 kept values <= X=(r*s)^2-eps: then true-count >= 16 so t16 <= X —
//   X is a PROVEN upper bound on the 16th-best d2, at zero extra cost.
// Pass 2 (exact): rescan shells 0..r_stop; full (d2, idx)-lexicographic
//   u64 insert (validated R1-R10 formula) gated by d2 <= X  -> ~2 inserts
//   per lane instead of ~16 (the R10 instruction sink).
// Entry enumeration: closed form with float-reciprocal division + fixup
//   (R10's rid/W and rid%W integer divisions were ~60-op expansions).
// All candidates with d2 <= X lie within Chebyshev cell-distance r_stop
// (offset < r*s per axis spans <= r cells), so pass 2's range is complete.
#define PHASE_A(R, W, EID)                                                   \
  int ms0 = 0, ms1 = 0;                                                      \
  if ((EID) < nent) {                                                        \
    const int rid = (EID) >> 1, side = (EID) & 1;                            \
    int dzq = (int)((float)rid * invW);                                      \
    if (dzq * (W) > rid) --dzq;                                              \
    else if ((dzq + 1) * (W) <= rid) ++dzq;                                  \
    const int dz = dzq - (R);                                                \
    const int dy = rid - dzq * (W) - (R);                                    \
    const int z2 = cz + dz, y2 = cy + dy;                                    \
    if ((unsigned)z2 < GRID && (unsigned)y2 < GRID) {                        \
      const int rowb = (z2 * GRID + y2) * GRID;                              \
      const bool bdry =                                                      \
          (dz == -(R)) || (dz == (R)) || (dy == -(R)) || (dy == (R));        \
      if (bdry) {                                                            \
        if (side == 0) {                                                     \
          const int xl = cx - (R) < 0 ? 0 : cx - (R);                        \
          const int xh = cx + (R) > GRID - 1 ? GRID - 1 : cx + (R);          \
          ms0 = ob[rowb + xl];                                               \
          ms1 = ob[rowb + xh + 1];                                           \
        }                                                                    \
      } else {                                                               \
        const int x2 = side ? cx + (R) : cx - (R);                           \
        if ((unsigned)x2 < GRID) {                                           \
          ms0 = ob[rowb + x2];                                               \
          ms1 = ob[rowb + x2 + 1];                                           \
        }                                                                    \
      }                                                                      \
    }                                                                        \
  }

__global__ __launch_bounds__(128) void k_query(const float4* __restrict__ spts,
                                               const u16* __restrict__ sidx,
                                               const int* __restrict__ offs,
                                               const float* __restrict__ gp,
                                               u16* __restrict__ oidx) {
  __shared__ u64 kb[16 * 128];  // 16 KB merge keys: kb[(slot<<7) + tid]
  const int tid = threadIdx.x;
  const int l = tid & 15;
  const int team = tid >> 4;
  const int lane = tid & 63;
  const int qid = blockIdx.x * 8 + team;
  const int b = qid >> 13, i = qid & 8191;
  const float4* __restrict__ sp = spts + (b << 13);
  const u16* __restrict__ sx = sidx + (b << 13);
  const int* __restrict__ ob = offs + b * NCELLP;
  const float* g = gp + b * 8;
  float4 q = sp[i];
  const float qsq = q.w;
  const unsigned orig = sx[i];
  const int cx = cellof(q.x, g[0], g[4]);
  const int cy = cellof(q.y, g[1], g[4]);
  const int cz = cellof(q.z, g[2], g[4]);
  const float s = g[3];
  const int tb = lane & 48;  // team base within wave

  // ---- pass 1: cheap 3-deep cascade + count-based stop ----
  float c1 = INFINITY, c2 = INFINITY, c3 = INFINITY;
  int rstop = GRID - 1;
  float X = INFINITY;
  for (int r = 0; r <= 2 * GRID; ++r) {
    const int W = 2 * r + 1;
    const int nent = 2 * W * W;
    const float invW = 1.0f / (float)W;
    for (int base = 0; base < nent; base += 16) {
      PHASE_A(r, W, base + l)
      unsigned m = (unsigned)((__ballot(ms1 > ms0) >> tb) & 0xFFFFull);
      while (m) {
        const int e = __ffs(m) - 1;
        m &= m - 1;
        const int s0 = __shfl(ms0, tb + e);
        const int s1 = __shfl(ms1, tb + e);
        for (int j = s0 + l; j < s1; j += 16) {
          float4 A = sp[j];
          float dot = q.x * A.x;
          dot = fmaf(q.y, A.y, dot);
          dot = fmaf(q.z, A.z, dot);
          float d2 = (qsq + A.w) - 2.0f * dot;
          float lo = fminf(d2, c1);
          float hi = fmaxf(d2, c1);
          c1 = lo;
          float lo2 = fminf(hi, c2);
          float hi2 = fmaxf(hi, c2);
          c2 = lo2;
          c3 = fminf(hi2, c3);
        }
      }
    }
    const float rs = (float)r * s;
    const float Xr = fmaf(rs, rs, -1e-4f);
    int cnt = (c1 <= Xr) + (c2 <= Xr) + (c3 <= Xr);
    cnt += __shfl_xor(cnt, 1);
    cnt += __shfl_xor(cnt, 2);
    cnt += __shfl_xor(cnt, 4);
    cnt += __shfl_xor(cnt, 8);
    if (cnt >= 16) {  // >=16 genuine distances <= Xr  =>  t16 <= Xr
      rstop = r;
      X = Xr;
      break;
    }
  }
  const int r2max = rstop < GRID - 1 ? rstop : GRID - 1;

  // ---- pass 2: exact gated top-16 ----
  u64 lst[16];
#pragma unroll
  for (int p = 0; p < 16; ++p) lst[p] = ~0ULL;

  for (int r = 0; r <= r2max; ++r) {
    const int W = 2 * r + 1;
    const int nent = 2 * W * W;
    const float invW = 1.0f / (float)W;
    for (int base = 0; base < nent; base += 16) {
      PHASE_A(r, W, base + l)
      unsigned m = (unsigned)((__ballot(ms1 > ms0) >> tb) & 0xFFFFull);
      while (m) {
        const int e = __ffs(m) - 1;
        m &= m - 1;
        const int s0 = __shfl(ms0, tb + e);
        const int s1 = __shfl(ms1, tb + e);
        for (int j = s0 + l; j < s1; j += 16) {
          float4 A = sp[j];
          float dot = q.x * A.x;
          dot = fmaf(q.y, A.y, dot);
          dot = fmaf(q.z, A.z, dot);
          float d2 = (qsq + A.w) - 2.0f * dot;
          if (d2 <= X) {
            unsigned oi = sx[j];
            unsigned u = __float_as_uint(d2);
            u ^= (0x80000000u | (unsigned)((int)u >> 31));
            u64 key = ((u64)u << 32) | oi;
            if (key < lst[15]) {
              u64 x = key;
#pragma unroll
              for (int p = 0; p < 16; ++p) {
                bool sw = x < lst[p];
                u64 a = lst[p];
                lst[p] = sw ? x : a;
                x = sw ? a : x;
              }
            }
          }
        }
      }
    }
  }

  // ---- merge 16 sorted lists per query (4 stages) ----
#pragma unroll
  for (int p = 0; p < 16; ++p) kb[(p << 7) + tid] = lst[p];
  __syncthreads();

  const int cbase = team << 4;
  u64 rb[16];
#pragma unroll
  for (int st = 0; st < 3; ++st) {
    const int stride = 1 << st;
    const int nm = 8 >> st;
    const bool act = (l < nm);
    if (act) {
      const int la = cbase + (2 * l) * stride;
      const int lb = la + stride;
      int pa = 0, pb = 0;
      u64 ka = kb[la], kv = kb[lb];
#pragma unroll
      for (int k = 0; k < 16; ++k) {
        bool ta = ka < kv;
        rb[k] = ta ? ka : kv;
        if (ta) {
          ++pa;
          ka = (pa < 16) ? kb[(pa << 7) + la] : ~0ULL;
        } else {
          ++pb;
          kv = (pb < 16) ? kb[(pb << 7) + lb] : ~0ULL;
        }
      }
    }
    __syncthreads();
    if (act) {
      const int la = cbase + (2 * l) * (1 << st);
#pragma unroll
      for (int p = 0; p < 16; ++p) kb[(p << 7) + la] = rb[p];
    }
    __syncthreads();
  }
  if (l == 0) {
    const int la = cbase, lb = cbase + 8;
    int pa = 0, pb = 0;
    u64 ka = kb[la], kv = kb[lb];
    unsigned pk[8];
#pragma unroll
    for (int k = 0; k < 16; ++k) {
      bool ta = ka < kv;
      u64 sel = ta ? ka : kv;
      unsigned id16 = (unsigned)(sel & 0xFFFFull);
      if (k & 1)
        pk[k >> 1] |= id16 << 16;
      else
        pk[k >> 1] = id16;
      if (ta) {
        ++pa;
        ka = (pa < 16) ? kb[(pa << 7) + la] : ~0ULL;
      } else {
        ++pb;
        kv = (pb < 16) ? kb[(pb << 7) + lb] : ~0ULL;
      }
    }
    unsigned* od = (unsigned*)(oidx + (((size_t)(b << 13) + orig) << 4));
#pragma unroll
    for (int k = 0; k < 8; ++k) od[k] = pk[k];
  }
}

// ---------------------------------------------------------------- K6: lt = feat @ lt_w + lt_b
__global__ __launch_bounds__(256) void k_lt(const float* __restrict__ feat,
                                            const float* __restrict__ ltw,
                                            const float* __restrict__ ltb,
                                            float* __restrict__ lt) {
  __shared__ float sw[64][196];
  __shared__ float sf[32][68];
  const int tid = threadIdx.x;
  const int r0 = blockIdx.x * 32;
#pragma unroll
  for (int i = 0; i < 12; ++i) {
    int v = tid + i * 256;
    float4 w4 = ((const float4*)ltw)[v];
    int row = (v * 4) / 192, col = (v * 4) % 192;
    *(float4*)&sw[row][col] = w4;
  }
#pragma unroll
  for (int i = 0; i < 2; ++i) {
    int v = tid + i * 256;
    int row = v >> 4, c4 = v & 15;
    float4 f4 = ((const float4*)(feat + (size_t)(r0 + row) * 64))[c4];
    *(float4*)&sf[row][c4 * 4] = f4;
  }
  __syncthreads();
  const int r = tid >> 3;
  const int c0 = (tid & 7) * 24;
  float acc[24];
#pragma unroll
  for (int ll = 0; ll < 24; ++ll) acc[ll] = ltb[c0 + ll];
#pragma unroll 4
  for (int j = 0; j < 64; ++j) {
    float f = sf[r][j];
#pragma unroll
    for (int l4 = 0; l4 < 6; ++l4) {
      float4 w4 = *(const float4*)&sw[j][c0 + l4 * 4];
      acc[l4 * 4 + 0] = fmaf(f, w4.x, acc[l4 * 4 + 0]);
      acc[l4 * 4 + 1] = fmaf(f, w4.y, acc[l4 * 4 + 1]);
      acc[l4 * 4 + 2] = fmaf(f, w4.z, acc[l4 * 4 + 2]);
      acc[l4 * 4 + 3] = fmaf(f, w4.w, acc[l4 * 4 + 3]);
    }
  }
  float* orow = lt + (size_t)(r0 + r) * 192 + c0;
#pragma unroll
  for (int l4 = 0; l4 < 6; ++l4)
    *(float4*)&orow[l4 * 4] = make_float4(acc[l4 * 4], acc[l4 * 4 + 1],
                                          acc[l4 * 4 + 2], acc[l4 * 4 + 3]);
}

// ---------------------------------------------------------------- K7: main
__global__ __launch_bounds__(256) void k_main(
    const float4* __restrict__ xytp, const float* __restrict__ lt,
    const u16* __restrict__ knn, const float* __restrict__ pe_w1,
    const float* __restrict__ pe_b1, const float* __restrict__ pe_w2,
    const float* __restrict__ pe_b2, const float* __restrict__ ln_g,
    const float* __restrict__ ln_b, float* __restrict__ out) {
  __shared__ float s_h[4][16][64];
  const int lane = threadIdx.x & 63;
  const int wave = threadIdx.x >> 6;
  const int pid = __builtin_amdgcn_readfirstlane(blockIdx.x * 4 + wave);
  const int b = pid >> 13;
  const int n = pid & 8191;

  float w1c[4];
#pragma unroll
  for (int d = 0; d < 4; ++d) w1c[d] = pe_w1[d * 64 + lane];
  const float b1c = pe_b1[lane];
  float w2c[64];
#pragma unroll
  for (int j = 0; j < 64; ++j) w2c[j] = pe_w2[j * 64 + lane];
  const float b2c = pe_b2[lane];
  const float gc = ln_g[lane], bc = ln_b[lane];

  int nb[16];
#pragma unroll
  for (int k = 0; k < 16; ++k) nb[k] = knn[pid * 16 + k];

  const float* __restrict__ ltb = lt + (size_t)(b << 13) * 192;
  float psi[16], alp[16];
#pragma unroll
  for (int k = 0; k < 16; ++k) {
    const float* row = ltb + (size_t)nb[k] * 192;
    psi[k] = row[64 + lane];
    alp[k] = row[128 + lane];
  }
  const float vc = ltb[(size_t)n * 192 + lane];

  const float4 qv = xytp[(b << 13) + n];
#pragma unroll
  for (int k = 0; k < 16; ++k) {
    float4 g = xytp[(b << 13) + nb[k]];
    float r0 = qv.x - g.x, r1 = qv.y - g.y, r2 = qv.z - g.z, r3 = qv.w - g.w;
    float h = fmaf(r3, w1c[3],
                   fmaf(r2, w1c[2], fmaf(r1, w1c[1], fmaf(r0, w1c[0], b1c))));
    s_h[wave][k][lane] = fmaxf(h, 0.0f);
  }
  __syncthreads();

  float pre[16], apd[16];
#pragma unroll
  for (int k = 0; k < 16; ++k) {
    float acc = b2c;
#pragma unroll
    for (int j4 = 0; j4 < 16; ++j4) {
      float4 h4 = *(const float4*)&s_h[wave][k][j4 * 4];
      acc = fmaf(h4.x, w2c[j4 * 4 + 0], acc);
      acc = fmaf(h4.y, w2c[j4 * 4 + 1], acc);
      acc = fmaf(h4.z, w2c[j4 * 4 + 2], acc);
      acc = fmaf(h4.w, w2c[j4 * 4 + 3], acc);
    }
    pre[k] = (vc - psi[k]) + acc;
    apd[k] = alp[k] + acc;
  }

  float xk[16], m = -INFINITY;
#pragma unroll
  for (int k = 0; k < 16; ++k) {
    float s = pre[k], ss = pre[k] * pre[k];
#pragma unroll
    for (int d = 1; d < 64; d <<= 1) {
      s += __shfl_xor(s, d);
      ss += __shfl_xor(ss, d);
    }
    float mu = s * 0.015625f;
    float var = fmaf(ss, 0.015625f, -mu * mu);
    float inv = 1.0f / sqrtf(var + 1e-5f);
    float lnv = fmaf((pre[k] - mu) * inv, gc, bc);
    xk[k] = lnv * 0.125f;
    m = fmaxf(m, xk[k]);
  }
  float se = 0.f, acc = 0.f;
#pragma unroll
  for (int k = 0; k < 16; ++k) {
    float e = __expf(xk[k] - m);
    se += e;
    acc = fmaf(e, apd[k], acc);
  }
  out[(size_t)pid * 64 + lane] = acc / se;
}

// ---------------------------------------------------------------- launch
extern "C" void kernel_launch(void* const* d_in, const int* in_sizes, int n_in,
                              void* d_out, int out_size, void* d_ws,
                              size_t ws_size, hipStream_t stream) {
  const float4* xytp = (const float4*)d_in[0];
  const float* features = (const float*)d_in[1];
  const float* pe_w1 = (const float*)d_in[2];
  const float* pe_b1 = (const float*)d_in[3];
  const float* pe_w2 = (const float*)d_in[4];
  const float* pe_b2 = (const float*)d_in[5];
  const float* lt_w = (const float*)d_in[6];
  const float* lt_b = (const float*)d_in[7];
  const float* ln_g = (const float*)d_in[8];
  const float* ln_b = (const float*)d_in[9];
  float* out = (float*)d_out;

  char* ws = (char*)d_ws;
  u16* idxbuf = (u16*)(ws + WS_IDX);
  float* lt = (float*)(ws + WS_LT);
  int* cnt = (int*)(ws + WS_CNT);
  int* offs = (int*)(ws + WS_OFF);
  int* curs = (int*)(ws + WS_CUR);
  float4* spts = (float4*)(ws + WS_SP);
  float* gp = (float*)(ws + WS_GP);
  u16* sidx = (u16*)(ws + WS_SIDX);

  k_minmax<<<BATCH, 256, 0, stream>>>(xytp, gp, cnt);
  k_count<<<(BATCH * NPTS) / 256, 256, 0, stream>>>(xytp, gp, cnt);
  k_scan<<<BATCH, 1024, 0, stream>>>(cnt, offs, curs);
  k_scatter<<<(BATCH * NPTS) / 256, 256, 0, stream>>>(xytp, gp, curs, spts,
                                                      sidx);
  k_query<<<(BATCH * NPTS) / 8, 128, 0, stream>>>(spts, sidx, offs, gp,
                                                  idxbuf);
  k_lt<<<(BATCH * NPTS) / 32, 256, 0, stream>>>(features, lt_w, lt_b, lt);
  k_main<<<(BATCH * NPTS) / 4, 256, 0, stream>>>(xytp, lt, idxbuf, pe_w1,
                                                 pe_b1, pe_w2, pe_b2, ln_g,
                                                 ln_b, out);
}

// Round 12
// 617.674 us; speedup vs baseline: 1.3452x; 1.3452x over previous
//
#include <hip/hip_runtime.h>
#include <stdint.h>

#define BATCH 4
#define NPTS 8192
#define KNN_K 16
#define GRID 24
#define NCELL (GRID * GRID * GRID)  // 13824
#define NCELLP (NCELL + 8)          // offs stride (sentinel slot)

typedef unsigned long long u64;
typedef unsigned short u16;

// ws layout (bytes)
#define WS_IDX 0u          // u16[4*8192*16]            = 1,048,576
#define WS_LT 1048576u     // float[4*8192*192]         = 25,165,824
#define WS_CNT 26214400u   // int[4*13824]              = 221,184
#define WS_OFF 26435584u   // int[4*13832]              = 221,312
#define WS_CUR 26656896u   // int[4*13824]              = 221,184
#define WS_SP 26878080u    // float4[4*8192]            = 524,288
#define WS_GP 27402368u    // float[4*8]                = 128
#define WS_SIDX 27402496u  // u16[4*8192]               = 65,536

__device__ __forceinline__ int cellof(float v, float o, float invs) {
  int c = (int)((v - o) * invs);
  return c < GRID - 1 ? c : GRID - 1;
}

// ---------------------------------------------------------------- K0: bbox + zero counters
__global__ __launch_bounds__(256) void k_minmax(const float4* __restrict__ xytp,
                                                float* __restrict__ gp,
                                                int* __restrict__ cnt) {
  const int b = blockIdx.x, t = threadIdx.x;
  for (int c = t; c < NCELL; c += 256) cnt[b * NCELL + c] = 0;
  const float4* pb = xytp + (b << 13);
  float mnx = INFINITY, mny = INFINITY, mnz = INFINITY;
  float mxx = -INFINITY, mxy = -INFINITY, mxz = -INFINITY;
  for (int i = t; i < NPTS; i += 256) {
    float4 p = pb[i];
    mnx = fminf(mnx, p.x); mny = fminf(mny, p.y); mnz = fminf(mnz, p.z);
    mxx = fmaxf(mxx, p.x); mxy = fmaxf(mxy, p.y); mxz = fmaxf(mxz, p.z);
  }
#pragma unroll
  for (int d = 1; d < 64; d <<= 1) {
    mnx = fminf(mnx, __shfl_xor(mnx, d)); mny = fminf(mny, __shfl_xor(mny, d));
    mnz = fminf(mnz, __shfl_xor(mnz, d)); mxx = fmaxf(mxx, __shfl_xor(mxx, d));
    mxy = fmaxf(mxy, __shfl_xor(mxy, d)); mxz = fmaxf(mxz, __shfl_xor(mxz, d));
  }
  __shared__ float red[4][6];
  const int lane = t & 63, wv = t >> 6;
  if (lane == 0) {
    red[wv][0] = mnx; red[wv][1] = mny; red[wv][2] = mnz;
    red[wv][3] = mxx; red[wv][4] = mxy; red[wv][5] = mxz;
  }
  __syncthreads();
  if (t == 0) {
    for (int w = 1; w < 4; ++w) {
      red[0][0] = fminf(red[0][0], red[w][0]);
      red[0][1] = fminf(red[0][1], red[w][1]);
      red[0][2] = fminf(red[0][2], red[w][2]);
      red[0][3] = fmaxf(red[0][3], red[w][3]);
      red[0][4] = fmaxf(red[0][4], red[w][4]);
      red[0][5] = fmaxf(red[0][5], red[w][5]);
    }
    float rmax = fmaxf(red[0][3] - red[0][0],
                       fmaxf(red[0][4] - red[0][1], red[0][5] - red[0][2]));
    float s = rmax / (float)GRID;
    float* g = gp + b * 8;
    g[0] = red[0][0]; g[1] = red[0][1]; g[2] = red[0][2];
    g[3] = s; g[4] = 1.0f / s;
  }
}

// ---------------------------------------------------------------- K2: count
__global__ __launch_bounds__(256) void k_count(const float4* __restrict__ xytp,
                                               const float* __restrict__ gp,
                                               int* __restrict__ cnt) {
  int i = blockIdx.x * 256 + threadIdx.x;
  int b = i >> 13;
  const float* g = gp + b * 8;
  float4 p = xytp[i];
  int cx = cellof(p.x, g[0], g[4]);
  int cy = cellof(p.y, g[1], g[4]);
  int cz = cellof(p.z, g[2], g[4]);
  atomicAdd(&cnt[b * NCELL + (cz * GRID + cy) * GRID + cx], 1);
}

// ---------------------------------------------------------------- K3: exclusive scan
__global__ __launch_bounds__(1024) void k_scan(const int* __restrict__ cnt,
                                               int* __restrict__ offs,
                                               int* __restrict__ curs) {
  __shared__ int wsum[16];
  const int b = blockIdx.x, t = threadIdx.x;
  const int base = b * NCELL;
  const int base2 = b * NCELLP;
  const int lo = t * 14;
  const int hi = lo + 14 < NCELL ? lo + 14 : NCELL;
  int s = 0;
  for (int c = lo; c < hi; ++c) s += cnt[base + c];
  const int lane = t & 63, wv = t >> 6;
  int v = s;
#pragma unroll
  for (int d = 1; d < 64; d <<= 1) {
    int u = __shfl_up(v, d);
    if (lane >= d) v += u;
  }
  if (lane == 63) wsum[wv] = v;
  __syncthreads();
  if (wv == 0 && lane < 16) {
    int x = wsum[lane];
#pragma unroll
    for (int d = 1; d < 16; d <<= 1) {
      int u = __shfl_up(x, d, 16);
      if (lane >= d) x += u;
    }
    wsum[lane] = x;
  }
  __syncthreads();
  int excl = (wv > 0 ? wsum[wv - 1] : 0) + v - s;
  for (int c = lo; c < hi; ++c) {
    offs[base2 + c] = excl;
    curs[base + c] = excl;
    excl += cnt[base + c];
  }
  if (hi == NCELL) offs[base2 + NCELL] = excl;  // == NPTS
}

// ---------------------------------------------------------------- K4: scatter
__global__ __launch_bounds__(256) void k_scatter(const float4* __restrict__ xytp,
                                                 const float* __restrict__ gp,
                                                 int* __restrict__ curs,
                                                 float4* __restrict__ spts,
                                                 u16* __restrict__ sidx) {
  int i = blockIdx.x * 256 + threadIdx.x;
  int b = i >> 13, n = i & 8191;
  const float* g = gp + b * 8;
  float4 p = xytp[i];
  int cx = cellof(p.x, g[0], g[4]);
  int cy = cellof(p.y, g[1], g[4]);
  int cz = cellof(p.z, g[2], g[4]);
  int pos = atomicAdd(&curs[b * NCELL + (cz * GRID + cy) * GRID + cx], 1);
  float sq = fmaf(p.z, p.z, fmaf(p.y, p.y, p.x * p.x));
  spts[(b << 13) + pos] = make_float4(p.x, p.y, p.z, sq);
  sidx[(b << 13) + pos] = (u16)n;
}

// ---------------------------------------------------------------- K5: grid KNN query
// R10 single-pass structure (best: 292us) + per-lane DEPTH-8 lists.
// Validity proof: any key a lane drops is >= that lane's final lst[7]
// (list only improves; dropped = old lst[7] >= final lst[7]).  So if every
// lane has lst[7] >= M (M = merged 16th key), nothing below M was dropped
// => merged top-16 exact.  Rare failure => block-uniform depth-16 redo.
// Stop: count-based (>=16 team-kept values <= (r*s)^2-eps => t16 bounded;
// proof validated in R11 pass 1).  Entry enumeration: float-recip div.
#define PHASE_A(R, W, EID)                                                   \
  int ms0 = 0, ms1 = 0;                                                      \
  if ((EID) < nent) {                                                        \
    const int rid = (EID) >> 1, side = (EID) & 1;                            \
    int dzq = (int)((float)rid * invW);                                      \
    if (dzq * (W) > rid) --dzq;                                              \
    else if ((dzq + 1) * (W) <= rid) ++dzq;                                  \
    const int dz = dzq - (R);                                                \
    const int dy = rid - dzq * (W) - (R);                                    \
    const int z2 = cz + dz, y2 = cy + dy;                                    \
    if ((unsigned)z2 < GRID && (unsigned)y2 < GRID) {                        \
      const int rowb = (z2 * GRID + y2) * GRID;                              \
      const bool bdry =                                                      \
          (dz == -(R)) || (dz == (R)) || (dy == -(R)) || (dy == (R));        \
      if (bdry) {                                                            \
        if (side == 0) {                                                     \
          const int xl = cx - (R) < 0 ? 0 : cx - (R);                        \
          const int xh = cx + (R) > GRID - 1 ? GRID - 1 : cx + (R);          \
          ms0 = ob[rowb + xl];                                               \
          ms1 = ob[rowb + xh + 1];                                           \
        }                                                                    \
      } else {                                                               \
        const int x2 = side ? cx + (R) : cx - (R);                          \
        if ((unsigned)x2 < GRID) {                                           \
          ms0 = ob[rowb + x2];                                               \
          ms1 = ob[rowb + x2 + 1];                                           \
        }                                                                    \
      }                                                                      \
    }                                                                        \
  }

// Full shell scan with depth-DEP sorted u64 insert + count-based stop.
#define SHELL_SCAN(LST, DEP)                                                 \
  for (int r = 0; r <= 2 * GRID; ++r) {                                      \
    const int W = 2 * r + 1;                                                 \
    const int nent = 2 * W * W;                                              \
    const float invW = 1.0f / (float)W;                                      \
    for (int base = 0; base < nent; base += 16) {                            \
      PHASE_A(r, W, base + l)                                                \
      unsigned m = (unsigned)((__ballot(ms1 > ms0) >> tb) & 0xFFFFull);      \
      while (m) {                                                            \
        const int e = __ffs(m) - 1;                                          \
        m &= m - 1;                                                          \
        const int s0 = __shfl(ms0, tb + e);                                  \
        const int s1 = __shfl(ms1, tb + e);                                  \
        for (int j = s0 + l; j < s1; j += 16) {                              \
          float4 A = sp[j];                                                  \
          unsigned oi = sx[j];                                               \
          float dot = q.x * A.x;                                             \
          dot = fmaf(q.y, A.y, dot);                                         \
          dot = fmaf(q.z, A.z, dot);                                         \
          float d2 = (qsq + A.w) - 2.0f * dot;                               \
          unsigned u = __float_as_uint(d2);                                  \
          u ^= (0x80000000u | (unsigned)((int)u >> 31));                     \
          u64 key = ((u64)u << 32) | oi;                                     \
          if (key < LST[(DEP)-1]) {                                          \
            u64 x = key;                                                     \
            _Pragma("unroll") for (int p = 0; p < (DEP); ++p) {              \
              bool sw = x < LST[p];                                          \
              u64 a = LST[p];                                                \
              LST[p] = sw ? x : a;                                           \
              x = sw ? a : x;                                                \
            }                                                                \
          }                                                                  \
        }                                                                    \
      }                                                                      \
    }                                                                        \
    const float rs = (float)r * s;                                           \
    const float Xr = fmaf(rs, rs, -1e-4f);                                   \
    unsigned ux = __float_as_uint(Xr);                                       \
    ux ^= (0x80000000u | (unsigned)((int)ux >> 31));                         \
    const u64 keyX = ((u64)ux << 32) | 0xFFFFFFFFull;                        \
    int cnt = 0;                                                             \
    _Pragma("unroll") for (int p = 0; p < (DEP); ++p) cnt += (LST[p] <= keyX);\
    cnt += __shfl_xor(cnt, 1);                                               \
    cnt += __shfl_xor(cnt, 2);                                               \
    cnt += __shfl_xor(cnt, 4);                                               \
    cnt += __shfl_xor(cnt, 8);                                               \
    if (cnt >= 16) break;                                                    \
  }

// Merge 16 sorted 16-deep lists (kb) per team; lane l==0 gets packed ids in
// pk and returns the 16th-best key.  Uniform control flow (internal barriers).
__device__ __forceinline__ u64 merge16(u64* kb, int tid, int l, int cbase,
                                       unsigned* pk) {
  u64 rb[16];
#pragma unroll
  for (int st = 0; st < 3; ++st) {
    const int stride = 1 << st;
    const int nm = 8 >> st;
    const bool act = (l < nm);
    if (act) {
      const int la = cbase + (2 * l) * stride;
      const int lb = la + stride;
      int pa = 0, pb = 0;
      u64 ka = kb[la], kv = kb[lb];
#pragma unroll
      for (int k = 0; k < 16; ++k) {
        bool ta = ka < kv;
        rb[k] = ta ? ka : kv;
        if (ta) {
          ++pa;
          ka = (pa < 16) ? kb[(pa << 7) + la] : ~0ULL;
        } else {
          ++pb;
          kv = (pb < 16) ? kb[(pb << 7) + lb] : ~0ULL;
        }
      }
    }
    __syncthreads();
    if (act) {
      const int la = cbase + (2 * l) * (1 << st);
#pragma unroll
      for (int p = 0; p < 16; ++p) kb[(p << 7) + la] = rb[p];
    }
    __syncthreads();
  }
  u64 Mkey = 0;
  if (l == 0) {
    const int la = cbase, lb = cbase + 8;
    int pa = 0, pb = 0;
    u64 ka = kb[la], kv = kb[lb];
#pragma unroll
    for (int k = 0; k < 16; ++k) {
      bool ta = ka < kv;
      u64 sel = ta ? ka : kv;
      unsigned id16 = (unsigned)(sel & 0xFFFFull);
      if (k & 1)
        pk[k >> 1] |= id16 << 16;
      else
        pk[k >> 1] = id16;
      if (k == 15) Mkey = sel;
      if (ta) {
        ++pa;
        ka = (pa < 16) ? kb[(pa << 7) + la] : ~0ULL;
      } else {
        ++pb;
        kv = (pb < 16) ? kb[(pb << 7) + lb] : ~0ULL;
      }
    }
  }
  return Mkey;
}

__global__ __launch_bounds__(128) void k_query(const float4* __restrict__ spts,
                                               const u16* __restrict__ sidx,
                                               const int* __restrict__ offs,
                                               const float* __restrict__ gp,
                                               u16* __restrict__ oidx) {
  __shared__ u64 kb[16 * 128];  // 16 KB merge keys: kb[(slot<<7) + tid]
  __shared__ int anybad;
  const int tid = threadIdx.x;
  const int l = tid & 15;
  const int team = tid >> 4;
  const int lane = tid & 63;
  const int qid = blockIdx.x * 8 + team;
  const int b = qid >> 13, i = qid & 8191;
  const float4* __restrict__ sp = spts + (b << 13);
  const u16* __restrict__ sx = sidx + (b << 13);
  const int* __restrict__ ob = offs + b * NCELLP;
  const float* g = gp + b * 8;
  float4 q = sp[i];
  const float qsq = q.w;
  const unsigned orig = sx[i];
  const int cx = cellof(q.x, g[0], g[4]);
  const int cy = cellof(q.y, g[1], g[4]);
  const int cz = cellof(q.z, g[2], g[4]);
  const float s = g[3];
  const int tb = lane & 48;  // team base within wave
  if (tid == 0) anybad = 0;

  // ---- depth-8 scan ----
  u64 lst[8];
#pragma unroll
  for (int p = 0; p < 8; ++p) lst[p] = ~0ULL;
  SHELL_SCAN(lst, 8)

  // ---- write keys (8 real + 8 pad) & merge ----
#pragma unroll
  for (int p = 0; p < 8; ++p) kb[(p << 7) + tid] = lst[p];
#pragma unroll
  for (int p = 8; p < 16; ++p) kb[(p << 7) + tid] = ~0ULL;
  __syncthreads();

  const int cbase = team << 4;
  unsigned pk[8];
  u64 Mkey = merge16(kb, tid, l, cbase, pk);

  // ---- validity: no lane dropped anything below M ----
  unsigned mlo = __shfl((int)(unsigned)(Mkey & 0xFFFFFFFFull), tb);
  unsigned mhi = __shfl((int)(unsigned)(Mkey >> 32), tb);
  u64 M = ((u64)mhi << 32) | mlo;
  if (lst[7] < M) anybad = 1;
  __syncthreads();

  if (anybad == 0) {
    if (l == 0) {
      unsigned* od = (unsigned*)(oidx + (((size_t)(b << 13) + orig) << 4));
#pragma unroll
      for (int k = 0; k < 8; ++k) od[k] = pk[k];
    }
    return;
  }

  // ---- essentially-never fallback: depth-16 redo (block-uniform) ----
  u64 lst2[16];
#pragma unroll
  for (int p = 0; p < 16; ++p) lst2[p] = ~0ULL;
  SHELL_SCAN(lst2, 16)
  __syncthreads();  // prior merge reads done before rewriting kb
#pragma unroll
  for (int p = 0; p < 16; ++p) kb[(p << 7) + tid] = lst2[p];
  __syncthreads();
  merge16(kb, tid, l, cbase, pk);
  if (l == 0) {
    unsigned* od = (unsigned*)(oidx + (((size_t)(b << 13) + orig) << 4));
#pragma unroll
    for (int k = 0; k < 8; ++k) od[k] = pk[k];
  }
}

// ---------------------------------------------------------------- K6: lt = feat @ lt_w + lt_b
__global__ __launch_bounds__(256) void k_lt(const float* __restrict__ feat,
                                            const float* __restrict__ ltw,
                                            const float* __restrict__ ltb,
                                            float* __restrict__ lt) {
  __shared__ float sw[64][196];
  __shared__ float sf[32][68];
  const int tid = threadIdx.x;
  const int r0 = blockIdx.x * 32;
#pragma unroll
  for (int i = 0; i < 12; ++i) {
    int v = tid + i * 256;
    float4 w4 = ((const float4*)ltw)[v];
    int row = (v * 4) / 192, col = (v * 4) % 192;
    *(float4*)&sw[row][col] = w4;
  }
#pragma unroll
  for (int i = 0; i < 2; ++i) {
    int v = tid + i * 256;
    int row = v >> 4, c4 = v & 15;
    float4 f4 = ((const float4*)(feat + (size_t)(r0 + row) * 64))[c4];
    *(float4*)&sf[row][c4 * 4] = f4;
  }
  __syncthreads();
  const int r = tid >> 3;
  const int c0 = (tid & 7) * 24;
  float acc[24];
#pragma unroll
  for (int ll = 0; ll < 24; ++ll) acc[ll] = ltb[c0 + ll];
#pragma unroll 4
  for (int j = 0; j < 64; ++j) {
    float f = sf[r][j];
#pragma unroll
    for (int l4 = 0; l4 < 6; ++l4) {
      float4 w4 = *(const float4*)&sw[j][c0 + l4 * 4];
      acc[l4 * 4 + 0] = fmaf(f, w4.x, acc[l4 * 4 + 0]);
      acc[l4 * 4 + 1] = fmaf(f, w4.y, acc[l4 * 4 + 1]);
      acc[l4 * 4 + 2] = fmaf(f, w4.z, acc[l4 * 4 + 2]);
      acc[l4 * 4 + 3] = fmaf(f, w4.w, acc[l4 * 4 + 3]);
    }
  }
  float* orow = lt + (size_t)(r0 + r) * 192 + c0;
#pragma unroll
  for (int l4 = 0; l4 < 6; ++l4)
    *(float4*)&orow[l4 * 4] = make_float4(acc[l4 * 4], acc[l4 * 4 + 1],
                                          acc[l4 * 4 + 2], acc[l4 * 4 + 3]);
}

// ---------------------------------------------------------------- K7: main
__global__ __launch_bounds__(256) void k_main(
    const float4* __restrict__ xytp, const float* __restrict__ lt,
    const u16* __restrict__ knn, const float* __restrict__ pe_w1,
    const float* __restrict__ pe_b1, const float* __restrict__ pe_w2,
    const float* __restrict__ pe_b2, const float* __restrict__ ln_g,
    const float* __restrict__ ln_b, float* __restrict__ out) {
  __shared__ float s_h[4][16][64];
  const int lane = threadIdx.x & 63;
  const int wave = threadIdx.x >> 6;
  const int pid = __builtin_amdgcn_readfirstlane(blockIdx.x * 4 + wave);
  const int b = pid >> 13;
  const int n = pid & 8191;

  float w1c[4];
#pragma unroll
  for (int d = 0; d < 4; ++d) w1c[d] = pe_w1[d * 64 + lane];
  const float b1c = pe_b1[lane];
  float w2c[64];
#pragma unroll
  for (int j = 0; j < 64; ++j) w2c[j] = pe_w2[j * 64 + lane];
  const float b2c = pe_b2[lane];
  const float gc = ln_g[lane], bc = ln_b[lane];

  int nb[16];
#pragma unroll
  for (int k = 0; k < 16; ++k) nb[k] = knn[pid * 16 + k];

  const float* __restrict__ ltb = lt + (size_t)(b << 13) * 192;
  float psi[16], alp[16];
#pragma unroll
  for (int k = 0; k < 16; ++k) {
    const float* row = ltb + (size_t)nb[k] * 192;
    psi[k] = row[64 + lane];
    alp[k] = row[128 + lane];
  }
  const float vc = ltb[(size_t)n * 192 + lane];

  const float4 qv = xytp[(b << 13) + n];
#pragma unroll
  for (int k = 0; k < 16; ++k) {
    float4 g = xytp[(b << 13) + nb[k]];
    float r0 = qv.x - g.x, r1 = qv.y - g.y, r2 = qv.z - g.z, r3 = qv.w - g.w;
    float h = fmaf(r3, w1c[3],
                   fmaf(r2, w1c[2], fmaf(r1, w1c[1], fmaf(r0, w1c[0], b1c))));
    s_h[wave][k][lane] = fmaxf(h, 0.0f);
  }
  __syncthreads();

  float pre[16], apd[16];
#pragma unroll
  for (int k = 0; k < 16; ++k) {
    float acc = b2c;
#pragma unroll
    for (int j4 = 0; j4 < 16; ++j4) {
      float4 h4 = *(const float4*)&s_h[wave][k][j4 * 4];
      acc = fmaf(h4.x, w2c[j4 * 4 + 0], acc);
      acc = fmaf(h4.y, w2c[j4 * 4 + 1], acc);
      acc = fmaf(h4.z, w2c[j4 * 4 + 2], acc);
      acc = fmaf(h4.w, w2c[j4 * 4 + 3], acc);
    }
    pre[k] = (vc - psi[k]) + acc;
    apd[k] = alp[k] + acc;
  }

  float xk[16], m = -INFINITY;
#pragma unroll
  for (int k = 0; k < 16; ++k) {
    float s = pre[k], ss = pre[k] * pre[k];
#pragma unroll
    for (int d = 1; d < 64; d <<= 1) {
      s += __shfl_xor(s, d);
      ss += __shfl_xor(ss, d);
    }
    float mu = s * 0.015625f;
    float var = fmaf(ss, 0.015625f, -mu * mu);
    float inv = 1.0f / sqrtf(var + 1e-5f);
    float lnv = fmaf((pre[k] - mu) * inv, gc, bc);
    xk[k] = lnv * 0.125f;
    m = fmaxf(m, xk[k]);
  }
  float se = 0.f, acc = 0.f;
#pragma unroll
  for (int k = 0; k < 16; ++k) {
    float e = __expf(xk[k] - m);
    se += e;
    acc = fmaf(e, apd[k], acc);
  }
  out[(size_t)pid * 64 + lane] = acc / se;
}

// ---------------------------------------------------------------- launch
extern "C" void kernel_launch(void* const* d_in, const int* in_sizes, int n_in,
                              void* d_out, int out_size, void* d_ws,
                              size_t ws_size, hipStream_t stream) {
  const float4* xytp = (const float4*)d_in[0];
  const float* features = (const float*)d_in[1];
  const float* pe_w1 = (const float*)d_in[2];
  const float* pe_b1 = (const float*)d_in[3];
  const float* pe_w2 = (const float*)d_in[4];
  const float* pe_b2 = (const float*)d_in[5];
  const float* lt_w = (const float*)d_in[6];
  const float* lt_b = (const float*)d_in[7];
  const float* ln_g = (const float*)d_in[8];
  const float* ln_b = (const float*)d_in[9];
  float* out = (float*)d_out;

  char* ws = (char*)d_ws;
  u16* idxbuf = (u16*)(ws + WS_IDX);
  float* lt = (float*)(ws + WS_LT);
  int* cnt = (int*)(ws + WS_CNT);
  int* offs = (int*)(ws + WS_OFF);
  int* curs = (int*)(ws + WS_CUR);
  float4* spts = (float4*)(ws + WS_SP);
  float* gp = (float*)(ws + WS_GP);
  u16* sidx = (u16*)(ws + WS_SIDX);

  k_minmax<<<BATCH, 256, 0, stream>>>(xytp, gp, cnt);
  k_count<<<(BATCH * NPTS) / 256, 256, 0, stream>>>(xytp, gp, cnt);
  k_scan<<<BATCH, 1024, 0, stream>>>(cnt, offs, curs);
  k_scatter<<<(BATCH * NPTS) / 256, 256, 0, stream>>>(xytp, gp, curs, spts,
                                                      sidx);
  k_query<<<(BATCH * NPTS) / 8, 128, 0, stream>>>(spts, sidx, offs, gp,
                                                  idxbuf);
  k_lt<<<(BATCH * NPTS) / 32, 256, 0, stream>>>(features, lt_w, lt_b, lt);
  k_main<<<(BATCH * NPTS) / 4, 256, 0, stream>>>(xytp, lt, idxbuf, pe_w1,
                                                 pe_b1, pe_w2, pe_b2, ln_g,
                                                 ln_b, out);
}